// Round 1
// baseline (536.037 us; speedup 1.0000x reference)
//
#include <hip/hip_runtime.h>

#define Bb 8
#define Nn 512
#define Ee 1024
#define Hh 128
#define Tt 8

__device__ __forceinline__ float sigm(float x){ return 1.0f/(1.0f + __expf(-x)); }
__device__ __forceinline__ float tanh_fast(float x){ return 2.0f/(1.0f + __expf(-2.0f*x)) - 1.0f; }

__device__ __forceinline__ void fma4(float* acc, float4 x, float4 w0, float4 w1, float4 w2, float4 w3){
  acc[0] += x.x*w0.x + x.y*w1.x + x.z*w2.x + x.w*w3.x;
  acc[1] += x.x*w0.y + x.y*w1.y + x.z*w2.y + x.w*w3.y;
  acc[2] += x.x*w0.z + x.y*w1.z + x.z*w2.z + x.w*w3.z;
  acc[3] += x.x*w0.w + x.y*w1.w + x.z*w2.w + x.w*w3.w;
}

// Extract src/tgt indices from the dense one-hot incidence matrices.
// n2e: [B,E,N] one_hot(src);  e2n: [B,N,E] = one_hot(tgt)^T.
__global__ void k_extract(const float4* __restrict__ n2e, const float4* __restrict__ e2n,
                          int* __restrict__ src, int* __restrict__ tgt){
  const int total1 = Bb*Ee*Nn/4;
  for (int i = blockIdx.x*blockDim.x + threadIdx.x; i < total1; i += gridDim.x*blockDim.x){
    float4 v = n2e[i];
    if (v.x!=0.f || v.y!=0.f || v.z!=0.f || v.w!=0.f){
      int base = i*4;
      int row = base >> 9;        // b*E + e   (N = 512)
      int n   = base & 511;
      if (v.x!=0.f) src[row] = n;
      if (v.y!=0.f) src[row] = n+1;
      if (v.z!=0.f) src[row] = n+2;
      if (v.w!=0.f) src[row] = n+3;
    }
  }
  const int total2 = Bb*Nn*Ee/4;
  for (int i = blockIdx.x*blockDim.x + threadIdx.x; i < total2; i += gridDim.x*blockDim.x){
    float4 v = e2n[i];
    if (v.x!=0.f || v.y!=0.f || v.z!=0.f || v.w!=0.f){
      int base = i*4;
      int row = base >> 10;       // b*N + n   (E = 1024)
      int e   = base & 1023;
      int b = row >> 9, n = row & 511;
      int* tp = tgt + b*Ee;
      if (v.x!=0.f) tp[e]   = n;
      if (v.y!=0.f) tp[e+1] = n;
      if (v.z!=0.f) tp[e+2] = n;
      if (v.w!=0.f) tp[e+3] = n;
    }
  }
}

// Transpose edge weights: W[t][h][d] -> WT[t][d][h]  (d-major, coalesced inner reads)
__global__ void k_transW(const float* __restrict__ W, float* __restrict__ WT){
  int i = blockIdx.x*blockDim.x + threadIdx.x;
  if (i >= Tt*Hh*Hh) return;
  int t = i >> 14;
  int h = (i >> 7) & 127;
  int d = i & 127;
  WT[(t*Hh + d)*Hh + h] = W[i];
}

// Per-graph counting sort of edges by type.
__global__ void k_sort(const int* __restrict__ ev, int* __restrict__ order, int* __restrict__ offs){
  __shared__ int cnt[Tt], offs_s[Tt+1], pos[Tt];
  int b = blockIdx.x, tid = threadIdx.x;
  if (tid < Tt) cnt[tid] = 0;
  __syncthreads();
  for (int e = tid; e < Ee; e += blockDim.x) atomicAdd(&cnt[ev[b*Ee+e]], 1);
  __syncthreads();
  if (tid == 0){ offs_s[0]=0; for (int t=0;t<Tt;t++) offs_s[t+1]=offs_s[t]+cnt[t]; }
  __syncthreads();
  if (tid < Tt) pos[tid] = offs_s[tid];
  if (tid < Tt+1) offs[b*(Tt+1)+tid] = offs_s[tid];
  __syncthreads();
  for (int e = tid; e < Ee; e += blockDim.x){
    int t = ev[b*Ee+e];
    int p = atomicAdd(&pos[t], 1);
    order[b*Ee + p] = e;
  }
}

// Type-batched edge message passing, both directions.
// dir 0: bw: emb = h[src], new = W_t @ emb, scatter-add to tgt
// dir 1: fw: emb = h[tgt], new = W_t @ emb, scatter-add to src
__global__ __launch_bounds__(256) void k_edge_mp(
    const float* __restrict__ h, const float* __restrict__ WT,
    const int* __restrict__ order, const int* __restrict__ offs,
    const int* __restrict__ src, const int* __restrict__ tgt,
    float* __restrict__ bw, float* __restrict__ fw)
{
  int x = blockIdx.x;
  int dir = x & 1;
  int bt  = x >> 1;
  int t = bt & 7, b = bt >> 3;
  int beg = offs[b*(Tt+1)+t], end = offs[b*(Tt+1)+t+1];
  int chunk0 = beg + blockIdx.y*32;
  if (chunk0 >= end) return;
  const int* gI = dir ? tgt : src;
  const int* sI = dir ? src : tgt;
  float* out = dir ? fw : bw;

  __shared__ float sEmb[32][Hh];   // 16 KB
  __shared__ float sW[64][Hh];     // 32 KB (k-chunk of W_t, d-major)
  int tid = threadIdx.x;
  int te = tid >> 5, tc = tid & 31;
  int e0 = te*4, c0 = tc*4;
  const float* WTt = WT + t*Hh*Hh;

  for (int chunk = chunk0; chunk < end; chunk += gridDim.y*32){
    int ne = min(32, end - chunk);
    __syncthreads();                      // protect sEmb from previous iteration's readers
    for (int i = tid; i < 32*Hh; i += 256){
      int e = i >> 7, c = i & 127;
      float v = 0.f;
      if (e < ne){
        int eid = order[b*Ee + chunk + e];
        v = h[(b*Nn + gI[b*Ee + eid])*Hh + c];
      }
      sEmb[e][c] = v;
    }
    float acc[4][4] = {};
    for (int kc = 0; kc < Hh; kc += 64){
      __syncthreads();                    // prior readers of sW done
      for (int i = tid; i < 64*Hh; i += 256){
        int d = i >> 7, c = i & 127;
        sW[d][c] = WTt[(kc + d)*Hh + c];
      }
      __syncthreads();
      #pragma unroll 4
      for (int k = 0; k < 64; k += 4){
        float4 evv[4], wv[4];
        #pragma unroll
        for (int j=0;j<4;j++) evv[j] = *(const float4*)&sEmb[e0+j][kc+k];
        #pragma unroll
        for (int j=0;j<4;j++) wv[j] = *(const float4*)&sW[k+j][c0];
        #pragma unroll
        for (int je=0;je<4;je++) fma4(acc[je], evv[je], wv[0], wv[1], wv[2], wv[3]);
      }
    }
    // scatter-add
    #pragma unroll
    for (int je=0;je<4;je++){
      int e = e0 + je;
      if (e < ne){
        int eid = order[b*Ee + chunk + e];
        int node = sI[b*Ee + eid];
        float* op = out + (size_t)(b*Nn + node)*Hh + c0;
        atomicAdd(op+0, acc[je][0]);
        atomicAdd(op+1, acc[je][1]);
        atomicAdd(op+2, acc[je][2]);
        atomicAdd(op+3, acc[je][3]);
      }
    }
  }
}

// Fused GatedFusion + GRU step for a 16-row tile (rows = b*N+n flattened).
__global__ __launch_bounds__(256) void k_fuse_gru(
    const float* __restrict__ hin, const float* __restrict__ fw, const float* __restrict__ bw,
    const float* __restrict__ Wf, const float* __restrict__ bfv,
    const float* __restrict__ Wz, const float* __restrict__ Wr, const float* __restrict__ Wt,
    float* __restrict__ hout)
{
  __shared__ float sF[16][Hh];   // fw, later agg
  __shared__ float sS[16][Hh];   // bw, later r*h
  __shared__ float sH[16][Hh];   // h
  int row0 = blockIdx.x * 16;
  int tid = threadIdx.x;
  for (int i = tid; i < 16*Hh; i += 256){
    int r = i >> 7, c = i & 127;
    sF[r][c] = fw[(size_t)(row0+r)*Hh + c];
    sS[r][c] = bw[(size_t)(row0+r)*Hh + c];
    sH[r][c] = hin[(size_t)(row0+r)*Hh + c];
  }
  __syncthreads();
  int te = tid >> 5, tc = tid & 31;
  int r0 = te*2, c0 = tc*4;

  // ---- Phase 1: zf = sigmoid([fw|bw|fw*bw|fw-bw] @ Wf + bf) ----
  float a0[4] = {0,0,0,0}, a1[4] = {0,0,0,0};
  #pragma unroll
  for (int sec = 0; sec < 4; ++sec){
    #pragma unroll 4
    for (int k = 0; k < Hh; k += 4){
      float4 fa = *(const float4*)&sF[r0][k];
      float4 fb = *(const float4*)&sF[r0+1][k];
      float4 sa = *(const float4*)&sS[r0][k];
      float4 sb = *(const float4*)&sS[r0+1][k];
      float4 xa, xb;
      if      (sec==0){ xa = fa; xb = fb; }
      else if (sec==1){ xa = sa; xb = sb; }
      else if (sec==2){ xa = make_float4(fa.x*sa.x, fa.y*sa.y, fa.z*sa.z, fa.w*sa.w);
                        xb = make_float4(fb.x*sb.x, fb.y*sb.y, fb.z*sb.z, fb.w*sb.w); }
      else            { xa = make_float4(fa.x-sa.x, fa.y-sa.y, fa.z-sa.z, fa.w-sa.w);
                        xb = make_float4(fb.x-sb.x, fb.y-sb.y, fb.z-sb.z, fb.w-sb.w); }
      const float* wp = Wf + (size_t)(sec*Hh + k)*Hh + c0;
      float4 w0 = *(const float4*)(wp);
      float4 w1 = *(const float4*)(wp + Hh);
      float4 w2 = *(const float4*)(wp + 2*Hh);
      float4 w3 = *(const float4*)(wp + 3*Hh);
      fma4(a0, xa, w0, w1, w2, w3);
      fma4(a1, xb, w0, w1, w2, w3);
    }
  }
  float bfx[4] = { bfv[c0], bfv[c0+1], bfv[c0+2], bfv[c0+3] };
  float ag0[4], ag1[4];
  #pragma unroll
  for (int j=0;j<4;j++){
    float zf0 = sigm(a0[j] + bfx[j]);
    float zf1 = sigm(a1[j] + bfx[j]);
    ag0[j] = (1.0f-zf0)*sF[r0][c0+j]   + zf0*sS[r0][c0+j];
    ag1[j] = (1.0f-zf1)*sF[r0+1][c0+j] + zf1*sS[r0+1][c0+j];
  }
  __syncthreads();
  #pragma unroll
  for (int j=0;j<4;j++){ sF[r0][c0+j] = ag0[j]; sF[r0+1][c0+j] = ag1[j]; }
  __syncthreads();

  // ---- Phase 2: z = sigmoid([h|agg]@Wz), r = sigmoid([h|agg]@Wr) ----
  float az0[4]={0,0,0,0}, az1[4]={0,0,0,0}, ar0[4]={0,0,0,0}, ar1[4]={0,0,0,0};
  #pragma unroll
  for (int sec = 0; sec < 2; ++sec){
    const float (*X)[Hh] = sec ? sF : sH;
    #pragma unroll 4
    for (int k = 0; k < Hh; k += 4){
      float4 xa = *(const float4*)&X[r0][k];
      float4 xb = *(const float4*)&X[r0+1][k];
      const float* wpz = Wz + (size_t)(sec*Hh + k)*Hh + c0;
      const float* wpr = Wr + (size_t)(sec*Hh + k)*Hh + c0;
      float4 z0 = *(const float4*)(wpz);
      float4 z1 = *(const float4*)(wpz + Hh);
      float4 z2 = *(const float4*)(wpz + 2*Hh);
      float4 z3 = *(const float4*)(wpz + 3*Hh);
      fma4(az0, xa, z0, z1, z2, z3);
      fma4(az1, xb, z0, z1, z2, z3);
      float4 r0v = *(const float4*)(wpr);
      float4 r1v = *(const float4*)(wpr + Hh);
      float4 r2v = *(const float4*)(wpr + 2*Hh);
      float4 r3v = *(const float4*)(wpr + 3*Hh);
      fma4(ar0, xa, r0v, r1v, r2v, r3v);
      fma4(ar1, xb, r0v, r1v, r2v, r3v);
    }
  }
  float zz0[4], zz1[4], rh0[4], rh1[4];
  #pragma unroll
  for (int j=0;j<4;j++){
    zz0[j] = sigm(az0[j]);
    zz1[j] = sigm(az1[j]);
    float rr0 = sigm(ar0[j]);
    float rr1 = sigm(ar1[j]);
    rh0[j] = rr0 * sH[r0][c0+j];
    rh1[j] = rr1 * sH[r0+1][c0+j];
  }
  __syncthreads();
  #pragma unroll
  for (int j=0;j<4;j++){ sS[r0][c0+j] = rh0[j]; sS[r0+1][c0+j] = rh1[j]; }
  __syncthreads();

  // ---- Phase 3: t = tanh([r*h|agg]@Wt);  h' = (1-z)*h + z*t ----
  float at0[4]={0,0,0,0}, at1[4]={0,0,0,0};
  #pragma unroll
  for (int sec = 0; sec < 2; ++sec){
    const float (*X)[Hh] = sec ? sF : sS;
    #pragma unroll 4
    for (int k = 0; k < Hh; k += 4){
      float4 xa = *(const float4*)&X[r0][k];
      float4 xb = *(const float4*)&X[r0+1][k];
      const float* wp = Wt + (size_t)(sec*Hh + k)*Hh + c0;
      float4 w0 = *(const float4*)(wp);
      float4 w1 = *(const float4*)(wp + Hh);
      float4 w2 = *(const float4*)(wp + 2*Hh);
      float4 w3 = *(const float4*)(wp + 3*Hh);
      fma4(at0, xa, w0, w1, w2, w3);
      fma4(at1, xb, w0, w1, w2, w3);
    }
  }
  #pragma unroll
  for (int j=0;j<4;j++){
    float t0 = tanh_fast(at0[j]);
    float t1 = tanh_fast(at1[j]);
    float h0 = sH[r0][c0+j],   h1v = sH[r0+1][c0+j];
    float o0 = (1.0f-zz0[j])*h0  + zz0[j]*t0;
    float o1 = (1.0f-zz1[j])*h1v + zz1[j]*t1;
    hout[(size_t)(row0+r0)*Hh   + c0+j] = o0;
    hout[(size_t)(row0+r0+1)*Hh + c0+j] = o1;
  }
}

extern "C" void kernel_launch(void* const* d_in, const int* in_sizes, int n_in,
                              void* d_out, int out_size, void* d_ws, size_t ws_size,
                              hipStream_t stream){
  const float* node_feature = (const float*)d_in[0];
  const int*   edge_vec     = (const int*)d_in[1];
  const float* n2e          = (const float*)d_in[2];
  const float* e2n          = (const float*)d_in[3];
  const float* Wtensor      = (const float*)d_in[4];
  const float* Wz           = (const float*)d_in[5];
  const float* Wr           = (const float*)d_in[6];
  const float* Wt           = (const float*)d_in[7];
  const float* Wf           = (const float*)d_in[8];
  const float* bf           = (const float*)d_in[9];
  float* out = (float*)d_out;

  char* p = (char*)d_ws;
  int* src   = (int*)p; p += Bb*Ee*4;
  int* tgt   = (int*)p; p += Bb*Ee*4;
  int* order = (int*)p; p += Bb*Ee*4;
  int* offs  = (int*)p; p += 4096;
  float* WT  = (float*)p; p += (size_t)Tt*Hh*Hh*4;
  float* bwp = (float*)p; p += (size_t)Bb*Nn*Hh*4;
  float* fwp = (float*)p; p += (size_t)Bb*Nn*Hh*4;
  float* h1  = (float*)p; p += (size_t)Bb*Nn*Hh*4;

  k_extract<<<1024, 256, 0, stream>>>((const float4*)n2e, (const float4*)e2n, src, tgt);
  k_transW<<<(Tt*Hh*Hh + 255)/256, 256, 0, stream>>>(Wtensor, WT);
  k_sort<<<Bb, 256, 0, stream>>>(edge_vec, order, offs);

  const float* hin = node_feature;
  float* houts[3] = { out, h1, out };
  for (int hop = 0; hop < 3; ++hop){
    hipMemsetAsync(bwp, 0, (size_t)2*Bb*Nn*Hh*4, stream);   // zero bw and fw (contiguous)
    k_edge_mp<<<dim3(Bb*Tt*2, 4), 256, 0, stream>>>(hin, WT, order, offs, src, tgt, bwp, fwp);
    k_fuse_gru<<<(Bb*Nn)/16, 256, 0, stream>>>(hin, fwp, bwp, Wf, bf, Wz, Wr, Wt, houts[hop]);
    hin = houts[hop];
  }
}

// Round 2
// 477.819 us; speedup vs baseline: 1.1218x; 1.1218x over previous
//
#include <hip/hip_runtime.h>

#define Bb 8
#define Nn 512
#define Ee 1024
#define Hh 128
#define Tt 8

#define FG_ROWS 16
#define FG_PAD 132     // +4 floats pad: x-row b128 reads land 2-way max

__device__ __forceinline__ float sigm(float x){ return 1.0f/(1.0f + __expf(-x)); }
__device__ __forceinline__ float tanh_fast(float x){ return 2.0f/(1.0f + __expf(-2.0f*x)) - 1.0f; }

__device__ __forceinline__ void fma4(float* acc, float4 x, float4 w0, float4 w1, float4 w2, float4 w3){
  acc[0] += x.x*w0.x + x.y*w1.x + x.z*w2.x + x.w*w3.x;
  acc[1] += x.x*w0.y + x.y*w1.y + x.z*w2.y + x.w*w3.y;
  acc[2] += x.x*w0.z + x.y*w1.z + x.z*w2.z + x.w*w3.z;
  acc[3] += x.x*w0.w + x.y*w1.w + x.z*w2.w + x.w*w3.w;
}

// Extract src/tgt indices from the dense one-hot incidence matrices.
__global__ void k_extract(const float4* __restrict__ n2e, const float4* __restrict__ e2n,
                          int* __restrict__ src, int* __restrict__ tgt){
  const int total1 = Bb*Ee*Nn/4;
  for (int i = blockIdx.x*blockDim.x + threadIdx.x; i < total1; i += gridDim.x*blockDim.x){
    float4 v = n2e[i];
    if (v.x!=0.f || v.y!=0.f || v.z!=0.f || v.w!=0.f){
      int base = i*4;
      int row = base >> 9;        // b*E + e   (N = 512)
      int n   = base & 511;
      if (v.x!=0.f) src[row] = n;
      if (v.y!=0.f) src[row] = n+1;
      if (v.z!=0.f) src[row] = n+2;
      if (v.w!=0.f) src[row] = n+3;
    }
  }
  const int total2 = Bb*Nn*Ee/4;
  for (int i = blockIdx.x*blockDim.x + threadIdx.x; i < total2; i += gridDim.x*blockDim.x){
    float4 v = e2n[i];
    if (v.x!=0.f || v.y!=0.f || v.z!=0.f || v.w!=0.f){
      int base = i*4;
      int row = base >> 10;       // b*N + n   (E = 1024)
      int e   = base & 1023;
      int b = row >> 9, n = row & 511;
      int* tp = tgt + b*Ee;
      if (v.x!=0.f) tp[e]   = n;
      if (v.y!=0.f) tp[e+1] = n;
      if (v.z!=0.f) tp[e+2] = n;
      if (v.w!=0.f) tp[e+3] = n;
    }
  }
}

// Transpose edge weights: W[t][h][d] -> WT[t][d][h]
__global__ void k_transW(const float* __restrict__ W, float* __restrict__ WT){
  int i = blockIdx.x*blockDim.x + threadIdx.x;
  if (i >= Tt*Hh*Hh) return;
  int t = i >> 14;
  int h = (i >> 7) & 127;
  int d = i & 127;
  WT[(t*Hh + d)*Hh + h] = W[i];
}

// Per-graph counting sort of edges by type.
__global__ void k_sort(const int* __restrict__ ev, int* __restrict__ order, int* __restrict__ offs){
  __shared__ int cnt[Tt], offs_s[Tt+1], pos[Tt];
  int b = blockIdx.x, tid = threadIdx.x;
  if (tid < Tt) cnt[tid] = 0;
  __syncthreads();
  for (int e = tid; e < Ee; e += blockDim.x) atomicAdd(&cnt[ev[b*Ee+e]], 1);
  __syncthreads();
  if (tid == 0){ offs_s[0]=0; for (int t=0;t<Tt;t++) offs_s[t+1]=offs_s[t]+cnt[t]; }
  __syncthreads();
  if (tid < Tt) pos[tid] = offs_s[tid];
  if (tid < Tt+1) offs[b*(Tt+1)+tid] = offs_s[tid];
  __syncthreads();
  for (int e = tid; e < Ee; e += blockDim.x){
    int t = ev[b*Ee+e];
    int p = atomicAdd(&pos[t], 1);
    order[b*Ee + p] = e;
  }
}

// Type-batched edge message passing, both directions. (unchanged this round)
__global__ __launch_bounds__(256) void k_edge_mp(
    const float* __restrict__ h, const float* __restrict__ WT,
    const int* __restrict__ order, const int* __restrict__ offs,
    const int* __restrict__ src, const int* __restrict__ tgt,
    float* __restrict__ bw, float* __restrict__ fw)
{
  int x = blockIdx.x;
  int dir = x & 1;
  int bt  = x >> 1;
  int t = bt & 7, b = bt >> 3;
  int beg = offs[b*(Tt+1)+t], end = offs[b*(Tt+1)+t+1];
  int chunk0 = beg + blockIdx.y*32;
  if (chunk0 >= end) return;
  const int* gI = dir ? tgt : src;
  const int* sI = dir ? src : tgt;
  float* out = dir ? fw : bw;

  __shared__ float sEmb[32][Hh];
  __shared__ float sW[64][Hh];
  int tid = threadIdx.x;
  int te = tid >> 5, tc = tid & 31;
  int e0 = te*4, c0 = tc*4;
  const float* WTt = WT + t*Hh*Hh;

  for (int chunk = chunk0; chunk < end; chunk += gridDim.y*32){
    int ne = min(32, end - chunk);
    __syncthreads();
    for (int i = tid; i < 32*Hh; i += 256){
      int e = i >> 7, c = i & 127;
      float v = 0.f;
      if (e < ne){
        int eid = order[b*Ee + chunk + e];
        v = h[(b*Nn + gI[b*Ee + eid])*Hh + c];
      }
      sEmb[e][c] = v;
    }
    float acc[4][4] = {};
    for (int kc = 0; kc < Hh; kc += 64){
      __syncthreads();
      for (int i = tid; i < 64*Hh; i += 256){
        int d = i >> 7, c = i & 127;
        sW[d][c] = WTt[(kc + d)*Hh + c];
      }
      __syncthreads();
      #pragma unroll 4
      for (int k = 0; k < 64; k += 4){
        float4 evv[4], wv[4];
        #pragma unroll
        for (int j=0;j<4;j++) evv[j] = *(const float4*)&sEmb[e0+j][kc+k];
        #pragma unroll
        for (int j=0;j<4;j++) wv[j] = *(const float4*)&sW[k+j][c0];
        #pragma unroll
        for (int je=0;je<4;je++) fma4(acc[je], evv[je], wv[0], wv[1], wv[2], wv[3]);
      }
    }
    #pragma unroll
    for (int je=0;je<4;je++){
      int e = e0 + je;
      if (e < ne){
        int eid = order[b*Ee + chunk + e];
        int node = sI[b*Ee + eid];
        float* op = out + (size_t)(b*Nn + node)*Hh + c0;
        atomicAdd(op+0, acc[je][0]);
        atomicAdd(op+1, acc[je][1]);
        atomicAdd(op+2, acc[je][2]);
        atomicAdd(op+3, acc[je][3]);
      }
    }
  }
}

// ---------------- fused GatedFusion + GRU, v2 ----------------
// 256 blocks x 512 threads; block = 16 rows x 128 cols.
// lane -> (row = lane>>2, colgroup = lane&3); wave w -> cols [w*16, w*16+16).
// Weights stream through a double-buffered 32-row LDS chunk pipeline:
//   issue global loads(chunk s+2) -> compute(chunk s, LDS) -> ds_write(chunk s+1) -> barrier.
// Chunk schedule s=0..39: 0-15 Wf, 16-23 Wz, 24-31 Wr, 32-39 Wt.

#define CK 32          // k-rows per W chunk
#define NS 40          // total chunks

__device__ __forceinline__ const float* chunk_ptr(int s, const float* Wf, const float* Wz,
                                                  const float* Wr, const float* Wt){
  if (s < 16) return Wf + s*CK*Hh;
  if (s < 24) return Wz + (s-16)*CK*Hh;
  if (s < 32) return Wr + (s-24)*CK*Hh;
  return Wt + (s-32)*CK*Hh;
}

__device__ __forceinline__ void load_chunk(const float* __restrict__ g, int tid, float4* pf){
  #pragma unroll
  for (int it = 0; it < 2; ++it)
    pf[it] = *(const float4*)(g + (((it<<9) + tid) << 2));
}
__device__ __forceinline__ void write_chunk(float* lds, int tid, const float4* pf){
  #pragma unroll
  for (int it = 0; it < 2; ++it)
    *(float4*)(lds + (((it<<9) + tid) << 2)) = pf[it];
}

__device__ __forceinline__ void chunk_gemm(const float (*X)[FG_PAD], int r, int kb,
                                           const float (*W)[Hh], int col0, float* acc){
  #pragma unroll
  for (int k = 0; k < CK; k += 4){
    float4 x  = *(const float4*)&X[r][kb+k];
    float4 w0 = *(const float4*)&W[k+0][col0];
    float4 w1 = *(const float4*)&W[k+1][col0];
    float4 w2 = *(const float4*)&W[k+2][col0];
    float4 w3 = *(const float4*)&W[k+3][col0];
    fma4(acc, x, w0, w1, w2, w3);
  }
}

__device__ __forceinline__ void chunk_gemm_fuse(const float (*A)[FG_PAD], const float (*B)[FG_PAD],
                                                int mode, int r, int kb, const float (*W)[Hh],
                                                int col0, float* acc){
  #pragma unroll
  for (int k = 0; k < CK; k += 4){
    float4 a = *(const float4*)&A[r][kb+k];
    float4 b = *(const float4*)&B[r][kb+k];
    float4 x;
    if (mode == 0) x = make_float4(a.x*b.x, a.y*b.y, a.z*b.z, a.w*b.w);
    else           x = make_float4(a.x-b.x, a.y-b.y, a.z-b.z, a.w-b.w);
    float4 w0 = *(const float4*)&W[k+0][col0];
    float4 w1 = *(const float4*)&W[k+1][col0];
    float4 w2 = *(const float4*)&W[k+2][col0];
    float4 w3 = *(const float4*)&W[k+3][col0];
    fma4(acc, x, w0, w1, w2, w3);
  }
}

__global__ __launch_bounds__(512) void k_fuse_gru(
    const float* __restrict__ hin, const float* __restrict__ fw, const float* __restrict__ bw,
    const float* __restrict__ Wf, const float* __restrict__ bfv,
    const float* __restrict__ Wz, const float* __restrict__ Wr, const float* __restrict__ Wt,
    float* __restrict__ hout)
{
  __shared__ float sF[FG_ROWS][FG_PAD];   // fw -> agg
  __shared__ float sS[FG_ROWS][FG_PAD];   // bw -> r*h
  __shared__ float sH[FG_ROWS][FG_PAD];   // h
  __shared__ float sW[2][CK][Hh];         // 32 KB double buffer

  int tid  = threadIdx.x;
  int row0 = blockIdx.x * FG_ROWS;
  int lane = tid & 63, w = tid >> 6;
  int r    = lane >> 2;
  int col0 = w*16 + (lane & 3)*4;

  // prologue: issue chunk0 loads, stage inputs, write chunk0, issue chunk1
  float4 pf[2];
  load_chunk(chunk_ptr(0, Wf, Wz, Wr, Wt), tid, pf);

  {
    int ir = tid >> 5;            // 0..15
    int k0 = (tid & 31) << 2;     // 0..124
    size_t gofs = (size_t)(row0 + ir)*Hh + k0;
    float4 fv = *(const float4*)&fw[gofs];
    float4 bv = *(const float4*)&bw[gofs];
    float4 hv = *(const float4*)&hin[gofs];
    *(float4*)&sF[ir][k0] = fv;
    *(float4*)&sS[ir][k0] = bv;
    *(float4*)&sH[ir][k0] = hv;
  }
  float4 bias4 = *(const float4*)&bfv[col0];

  write_chunk(&sW[0][0][0], tid, pf);
  load_chunk(chunk_ptr(1, Wf, Wz, Wr, Wt), tid, pf);
  __syncthreads();

  // ---- Phase 1: af = [fw|bw|fw*bw|fw-bw] @ Wf ----
  float af[4] = {0,0,0,0};
  for (int s = 0; s < 16; ++s){
    const float (*Wb)[Hh] = (const float (*)[Hh])sW[s&1];
    int sec = s >> 2, kb = (s & 3)*CK;
    if      (sec == 0) chunk_gemm(sF, r, kb, Wb, col0, af);
    else if (sec == 1) chunk_gemm(sS, r, kb, Wb, col0, af);
    else if (sec == 2) chunk_gemm_fuse(sF, sS, 0, r, kb, Wb, col0, af);
    else               chunk_gemm_fuse(sF, sS, 1, r, kb, Wb, col0, af);
    write_chunk(&sW[(s+1)&1][0][0], tid, pf);                 // chunk s+1 (waits its loads)
    load_chunk(chunk_ptr(s+2, Wf, Wz, Wr, Wt), tid, pf);      // chunk s+2 in flight
    __syncthreads();
  }

  // agg = (1-zf)*fw + zf*bw ; overwrite sF with agg
  float agv[4];
  {
    float bb[4] = {bias4.x, bias4.y, bias4.z, bias4.w};
    #pragma unroll
    for (int j = 0; j < 4; ++j){
      float z = sigm(af[j] + bb[j]);
      agv[j] = (1.0f - z)*sF[r][col0+j] + z*sS[r][col0+j];
    }
  }
  *(float4*)&sF[r][col0] = make_float4(agv[0], agv[1], agv[2], agv[3]);
  __syncthreads();

  // ---- Phase 2: az = [h|agg]@Wz ; ar = [h|agg]@Wr ----
  float az[4] = {0,0,0,0}, ar[4] = {0,0,0,0};
  for (int s = 16; s < 32; ++s){
    const float (*Wb)[Hh] = (const float (*)[Hh])sW[s&1];
    int q = s - 16;                 // 0..15
    int kb = (q & 3)*CK;
    const float (*X)[FG_PAD] = ((q & 4) ? sF : sH);   // q%8: 0-3 h-part, 4-7 agg-part
    if (q < 8) chunk_gemm(X, r, kb, Wb, col0, az);
    else       chunk_gemm(X, r, kb, Wb, col0, ar);
    write_chunk(&sW[(s+1)&1][0][0], tid, pf);
    load_chunk(chunk_ptr(s+2, Wf, Wz, Wr, Wt), tid, pf);
    __syncthreads();
  }

  // rh = sigmoid(ar) * h ; overwrite sS with rh ; keep z in regs
  float zz[4];
  {
    float rh[4];
    #pragma unroll
    for (int j = 0; j < 4; ++j){
      zz[j] = sigm(az[j]);
      rh[j] = sigm(ar[j]) * sH[r][col0+j];
    }
    *(float4*)&sS[r][col0] = make_float4(rh[0], rh[1], rh[2], rh[3]);
  }
  __syncthreads();

  // ---- Phase 3: at = [rh|agg] @ Wt ----
  float at[4] = {0,0,0,0};
  for (int s = 32; s < NS; ++s){
    const float (*Wb)[Hh] = (const float (*)[Hh])sW[s&1];
    int q = s - 32;
    int kb = (q & 3)*CK;
    const float (*X)[FG_PAD] = ((q & 4) ? sF : sS);
    chunk_gemm(X, r, kb, Wb, col0, at);
    if (s < NS-1){
      write_chunk(&sW[(s+1)&1][0][0], tid, pf);
      if (s < NS-2) load_chunk(chunk_ptr(s+2, Wf, Wz, Wr, Wt), tid, pf);
      __syncthreads();
    }
  }

  // h' = (1-z)*h + z*tanh(at)
  float o[4];
  #pragma unroll
  for (int j = 0; j < 4; ++j){
    float t = tanh_fast(at[j]);
    o[j] = (1.0f - zz[j])*sH[r][col0+j] + zz[j]*t;
  }
  *(float4*)&hout[(size_t)(row0 + r)*Hh + col0] = make_float4(o[0], o[1], o[2], o[3]);
}

extern "C" void kernel_launch(void* const* d_in, const int* in_sizes, int n_in,
                              void* d_out, int out_size, void* d_ws, size_t ws_size,
                              hipStream_t stream){
  const float* node_feature = (const float*)d_in[0];
  const int*   edge_vec     = (const int*)d_in[1];
  const float* n2e          = (const float*)d_in[2];
  const float* e2n          = (const float*)d_in[3];
  const float* Wtensor      = (const float*)d_in[4];
  const float* Wz           = (const float*)d_in[5];
  const float* Wr           = (const float*)d_in[6];
  const float* Wt           = (const float*)d_in[7];
  const float* Wf           = (const float*)d_in[8];
  const float* bf           = (const float*)d_in[9];
  float* out = (float*)d_out;

  char* p = (char*)d_ws;
  int* src   = (int*)p; p += Bb*Ee*4;
  int* tgt   = (int*)p; p += Bb*Ee*4;
  int* order = (int*)p; p += Bb*Ee*4;
  int* offs  = (int*)p; p += 4096;
  float* WT  = (float*)p; p += (size_t)Tt*Hh*Hh*4;
  float* bwp = (float*)p; p += (size_t)Bb*Nn*Hh*4;
  float* fwp = (float*)p; p += (size_t)Bb*Nn*Hh*4;
  float* h1  = (float*)p; p += (size_t)Bb*Nn*Hh*4;

  k_extract<<<1024, 256, 0, stream>>>((const float4*)n2e, (const float4*)e2n, src, tgt);
  k_transW<<<(Tt*Hh*Hh + 255)/256, 256, 0, stream>>>(Wtensor, WT);
  k_sort<<<Bb, 256, 0, stream>>>(edge_vec, order, offs);

  const float* hin = node_feature;
  float* houts[3] = { out, h1, out };
  for (int hop = 0; hop < 3; ++hop){
    hipMemsetAsync(bwp, 0, (size_t)2*Bb*Nn*Hh*4, stream);   // zero bw and fw (contiguous)
    k_edge_mp<<<dim3(Bb*Tt*2, 4), 256, 0, stream>>>(hin, WT, order, offs, src, tgt, bwp, fwp);
    k_fuse_gru<<<(Bb*Nn)/FG_ROWS, 512, 0, stream>>>(hin, fwp, bwp, Wf, bf, Wz, Wr, Wt, houts[hop]);
    hin = houts[hop];
  }
}

// Round 3
// 474.377 us; speedup vs baseline: 1.1300x; 1.0073x over previous
//
#include <hip/hip_runtime.h>

#define Bb 8
#define Nn 512
#define Ee 1024
#define Hh 128
#define Tt 8
#define FPAD 132

__device__ __forceinline__ float sigm(float x){ return 1.0f/(1.0f + __expf(-x)); }
__device__ __forceinline__ float tanh_fast(float x){ return 2.0f/(1.0f + __expf(-2.0f*x)) - 1.0f; }

__device__ __forceinline__ void fma4(float* acc, float4 x, float4 w0, float4 w1, float4 w2, float4 w3){
  acc[0] += x.x*w0.x + x.y*w1.x + x.z*w2.x + x.w*w3.x;
  acc[1] += x.x*w0.y + x.y*w1.y + x.z*w2.y + x.w*w3.y;
  acc[2] += x.x*w0.z + x.y*w1.z + x.z*w2.z + x.w*w3.z;
  acc[3] += x.x*w0.w + x.y*w1.w + x.z*w2.w + x.w*w3.w;
}

// Extract src/tgt indices from the dense one-hot incidence matrices.
__global__ void k_extract(const float4* __restrict__ n2e, const float4* __restrict__ e2n,
                          int* __restrict__ src, int* __restrict__ tgt){
  const int total1 = Bb*Ee*Nn/4;
  for (int i = blockIdx.x*blockDim.x + threadIdx.x; i < total1; i += gridDim.x*blockDim.x){
    float4 v = n2e[i];
    if (v.x!=0.f || v.y!=0.f || v.z!=0.f || v.w!=0.f){
      int base = i*4;
      int row = base >> 9;        // b*E + e   (N = 512)
      int n   = base & 511;
      if (v.x!=0.f) src[row] = n;
      if (v.y!=0.f) src[row] = n+1;
      if (v.z!=0.f) src[row] = n+2;
      if (v.w!=0.f) src[row] = n+3;
    }
  }
  const int total2 = Bb*Nn*Ee/4;
  for (int i = blockIdx.x*blockDim.x + threadIdx.x; i < total2; i += gridDim.x*blockDim.x){
    float4 v = e2n[i];
    if (v.x!=0.f || v.y!=0.f || v.z!=0.f || v.w!=0.f){
      int base = i*4;
      int row = base >> 10;       // b*N + n   (E = 1024)
      int e   = base & 1023;
      int b = row >> 9, n = row & 511;
      int* tp = tgt + b*Ee;
      if (v.x!=0.f) tp[e]   = n;
      if (v.y!=0.f) tp[e+1] = n;
      if (v.z!=0.f) tp[e+2] = n;
      if (v.w!=0.f) tp[e+3] = n;
    }
  }
}

// Transpose edge weights: W[t][h][d] -> WT[t][d][h]  (k-major rows, out-col contiguous)
__global__ void k_transW(const float* __restrict__ W, float* __restrict__ WT){
  int i = blockIdx.x*blockDim.x + threadIdx.x;
  if (i >= Tt*Hh*Hh) return;
  int t = i >> 14;
  int h = (i >> 7) & 127;
  int d = i & 127;
  WT[(t*Hh + d)*Hh + h] = W[i];
}

// Fold Wf: af = fw@(Wa+Wd) + bw@(Wb-Wd) + (fw*bw)@Wc   -> Ff[384][128]
__global__ void k_prep(const float* __restrict__ Wf, float* __restrict__ Ff){
  int i = blockIdx.x*blockDim.x + threadIdx.x;
  if (i >= 384*Hh) return;
  int r = i >> 7, c = i & 127;
  float v;
  if (r < 128)      v = Wf[r*Hh + c] + Wf[(r+384)*Hh + c];
  else if (r < 256) v = Wf[r*Hh + c] - Wf[(r+256)*Hh + c];
  else              v = Wf[r*Hh + c];
  Ff[i] = v;
}

// Per-graph counting sort of edges by type.
__global__ void k_sort(const int* __restrict__ ev, int* __restrict__ order, int* __restrict__ offs){
  __shared__ int cnt[Tt], offs_s[Tt+1], pos[Tt];
  int b = blockIdx.x, tid = threadIdx.x;
  if (tid < Tt) cnt[tid] = 0;
  __syncthreads();
  for (int e = tid; e < Ee; e += blockDim.x) atomicAdd(&cnt[ev[b*Ee+e]], 1);
  __syncthreads();
  if (tid == 0){ offs_s[0]=0; for (int t=0;t<Tt;t++) offs_s[t+1]=offs_s[t]+cnt[t]; }
  __syncthreads();
  if (tid < Tt) pos[tid] = offs_s[tid];
  if (tid < Tt+1) offs[b*(Tt+1)+tid] = offs_s[tid];
  __syncthreads();
  for (int e = tid; e < Ee; e += blockDim.x){
    int t = ev[b*Ee+e];
    int p = atomicAdd(&pos[t], 1);
    order[b*Ee + p] = e;
  }
}

// ------------- edge message passing v3: W from global (L1/L2), emb in LDS -------------
// block = (b, t, dir); 256 threads; wave w covers cols [w*32, w*32+32).
// lane: e0 = ((lane>>3)&7)*4 (4 edges), c0 = w*32 + (lane&7)*4 (4 cols).
__global__ __launch_bounds__(256) void k_edge_mp(
    const float* __restrict__ h, const float* __restrict__ WT,
    const int* __restrict__ order, const int* __restrict__ offs,
    const int* __restrict__ src, const int* __restrict__ tgt,
    float* __restrict__ bw, float* __restrict__ fw)
{
  int x = blockIdx.x;
  int dir = x & 1, bt = x >> 1, t = bt & 7, b = bt >> 3;
  int beg = offs[b*(Tt+1)+t], end = offs[b*(Tt+1)+t+1];
  int chunk0 = beg + blockIdx.y*32;
  if (chunk0 >= end) return;
  const int* gI = dir ? tgt : src;
  const int* sI = dir ? src : tgt;
  float* out = dir ? fw : bw;

  __shared__ float sEmb[32][FPAD];
  __shared__ int sNode[32];
  int tid = threadIdx.x, lane = tid & 63, w = tid >> 6;
  int e0 = (lane >> 3)*4;
  int c0 = w*32 + (lane & 7)*4;
  const float* __restrict__ Wg = WT + t*Hh*Hh + c0;

  for (int chunk = chunk0; chunk < end; chunk += gridDim.y*32){
    int ne = min(32, end - chunk);
    __syncthreads();                    // protect sEmb/sNode from prev iteration readers
    {
      int ir = tid >> 5, k0 = (tid & 31)*4;
      #pragma unroll
      for (int rr = 0; rr < 4; ++rr){
        int e = ir + rr*8;
        float4 v = {0.f,0.f,0.f,0.f};
        if (e < ne){
          int eid = order[b*Ee + chunk + e];
          v = *(const float4*)&h[(size_t)(b*Nn + gI[b*Ee + eid])*Hh + k0];
        }
        *(float4*)&sEmb[e][k0] = v;
      }
      if (tid < 32){
        int nd = -1;
        if (tid < ne){ int eid = order[b*Ee + chunk + tid]; nd = sI[b*Ee + eid]; }
        sNode[tid] = nd;
      }
    }
    __syncthreads();

    float acc[4][4] = {};
    #pragma unroll 4
    for (int k = 0; k < Hh; k += 4){
      float4 w0 = *(const float4*)&Wg[(size_t)(k+0)*Hh];
      float4 w1 = *(const float4*)&Wg[(size_t)(k+1)*Hh];
      float4 w2 = *(const float4*)&Wg[(size_t)(k+2)*Hh];
      float4 w3 = *(const float4*)&Wg[(size_t)(k+3)*Hh];
      #pragma unroll
      for (int j = 0; j < 4; ++j){
        float4 xv = *(const float4*)&sEmb[e0+j][k];
        fma4(acc[j], xv, w0, w1, w2, w3);
      }
    }
    #pragma unroll
    for (int j = 0; j < 4; ++j){
      int node = sNode[e0+j];
      if (node >= 0){
        float* op = out + (size_t)(b*Nn + node)*Hh + c0;
        atomicAdd(op+0, acc[j][0]);
        atomicAdd(op+1, acc[j][1]);
        atomicAdd(op+2, acc[j][2]);
        atomicAdd(op+3, acc[j][3]);
      }
    }
  }
}

// ------------- fused GatedFusion + GRU v3: W from global, X in LDS, 4 barriers -------------
__device__ __forceinline__ void gemm_sec(const float (*X)[FPAD], int r,
                                         const float* __restrict__ Wg, float* acc){
  #pragma unroll 4
  for (int k = 0; k < 128; k += 4){
    float4 x  = *(const float4*)&X[r][k];
    float4 w0 = *(const float4*)&Wg[(size_t)(k+0)*Hh];
    float4 w1 = *(const float4*)&Wg[(size_t)(k+1)*Hh];
    float4 w2 = *(const float4*)&Wg[(size_t)(k+2)*Hh];
    float4 w3 = *(const float4*)&Wg[(size_t)(k+3)*Hh];
    fma4(acc, x, w0, w1, w2, w3);
  }
}

__device__ __forceinline__ void gemm_prod(const float (*A)[FPAD], const float (*B)[FPAD], int r,
                                          const float* __restrict__ Wg, float* acc){
  #pragma unroll 4
  for (int k = 0; k < 128; k += 4){
    float4 a = *(const float4*)&A[r][k];
    float4 b = *(const float4*)&B[r][k];
    float4 x = make_float4(a.x*b.x, a.y*b.y, a.z*b.z, a.w*b.w);
    float4 w0 = *(const float4*)&Wg[(size_t)(k+0)*Hh];
    float4 w1 = *(const float4*)&Wg[(size_t)(k+1)*Hh];
    float4 w2 = *(const float4*)&Wg[(size_t)(k+2)*Hh];
    float4 w3 = *(const float4*)&Wg[(size_t)(k+3)*Hh];
    fma4(acc, x, w0, w1, w2, w3);
  }
}

__device__ __forceinline__ void gemm2(const float (*X)[FPAD], int r,
                                      const float* __restrict__ Wa, const float* __restrict__ Wb,
                                      float* acc1, float* acc2){
  #pragma unroll 4
  for (int k = 0; k < 128; k += 4){
    float4 x  = *(const float4*)&X[r][k];
    float4 a0 = *(const float4*)&Wa[(size_t)(k+0)*Hh];
    float4 a1 = *(const float4*)&Wa[(size_t)(k+1)*Hh];
    float4 a2 = *(const float4*)&Wa[(size_t)(k+2)*Hh];
    float4 a3 = *(const float4*)&Wa[(size_t)(k+3)*Hh];
    fma4(acc1, x, a0, a1, a2, a3);
    float4 b0 = *(const float4*)&Wb[(size_t)(k+0)*Hh];
    float4 b1 = *(const float4*)&Wb[(size_t)(k+1)*Hh];
    float4 b2 = *(const float4*)&Wb[(size_t)(k+2)*Hh];
    float4 b3 = *(const float4*)&Wb[(size_t)(k+3)*Hh];
    fma4(acc2, x, b0, b1, b2, b3);
  }
}

__global__ __launch_bounds__(512) void k_fuse_gru(
    const float* __restrict__ hin, const float* __restrict__ fw, const float* __restrict__ bw,
    const float* __restrict__ Ff, const float* __restrict__ bfv,
    const float* __restrict__ Wz, const float* __restrict__ Wr, const float* __restrict__ Wt,
    float* __restrict__ hout, float* __restrict__ zf, float* __restrict__ zb)
{
  __shared__ float sF[16][FPAD];   // fw -> agg
  __shared__ float sS[16][FPAD];   // bw -> r*h
  __shared__ float sH[16][FPAD];   // h
  int tid  = threadIdx.x;
  int row0 = blockIdx.x * 16;
  int lane = tid & 63, w = tid >> 6;
  int r    = lane >> 2;
  int c0   = w*16 + (lane & 3)*4;

  {
    int ir = tid >> 5, k0 = (tid & 31)*4;
    size_t g = (size_t)(row0 + ir)*Hh + k0;
    *(float4*)&sF[ir][k0] = *(const float4*)&fw[g];
    *(float4*)&sS[ir][k0] = *(const float4*)&bw[g];
    *(float4*)&sH[ir][k0] = *(const float4*)&hin[g];
  }
  float4 bias = *(const float4*)&bfv[c0];
  __syncthreads();

  // ---- P1: af = fw@F[0:128] + bw@F[128:256] + (fw*bw)@F[256:384] ----
  float af[4] = {0,0,0,0};
  gemm_sec (sF, r, Ff + c0,            af);
  gemm_sec (sS, r, Ff + 128*Hh + c0,   af);
  gemm_prod(sF, sS, r, Ff + 256*Hh + c0, af);

  float agv[4];
  {
    float bb[4] = {bias.x, bias.y, bias.z, bias.w};
    #pragma unroll
    for (int j = 0; j < 4; ++j){
      float z = sigm(af[j] + bb[j]);
      agv[j] = (1.0f - z)*sF[r][c0+j] + z*sS[r][c0+j];
    }
  }
  __syncthreads();                              // all P1 reads of sF/sS done
  *(float4*)&sF[r][c0] = make_float4(agv[0], agv[1], agv[2], agv[3]);
  __syncthreads();                              // agg visible

  // ---- P2: az = [h|agg]@Wz, ar = [h|agg]@Wr  (X shared) ----
  float az[4] = {0,0,0,0}, ar[4] = {0,0,0,0};
  gemm2(sH, r, Wz + c0,          Wr + c0,          az, ar);
  gemm2(sF, r, Wz + 128*Hh + c0, Wr + 128*Hh + c0, az, ar);

  float zz[4];
  {
    float rh[4];
    #pragma unroll
    for (int j = 0; j < 4; ++j){
      zz[j] = sigm(az[j]);
      rh[j] = sigm(ar[j]) * sH[r][c0+j];
    }
    *(float4*)&sS[r][c0] = make_float4(rh[0], rh[1], rh[2], rh[3]);
  }
  __syncthreads();                              // rh visible

  // ---- P3: at = [rh|agg]@Wt ----
  float at[4] = {0,0,0,0};
  gemm_sec(sS, r, Wt + c0,          at);
  gemm_sec(sF, r, Wt + 128*Hh + c0, at);

  float o[4];
  #pragma unroll
  for (int j = 0; j < 4; ++j){
    float t = tanh_fast(at[j]);
    o[j] = (1.0f - zz[j])*sH[r][c0+j] + zz[j]*t;
  }
  *(float4*)&hout[(size_t)(row0 + r)*Hh + c0] = make_float4(o[0], o[1], o[2], o[3]);

  // zero fw/bw slices for the next hop (replaces per-hop memsets)
  {
    int ir = tid >> 5, k0 = (tid & 31)*4;
    size_t g = (size_t)(row0 + ir)*Hh + k0;
    float4 zv = {0.f,0.f,0.f,0.f};
    *(float4*)&zf[g] = zv;
    *(float4*)&zb[g] = zv;
  }
}

extern "C" void kernel_launch(void* const* d_in, const int* in_sizes, int n_in,
                              void* d_out, int out_size, void* d_ws, size_t ws_size,
                              hipStream_t stream){
  const float* node_feature = (const float*)d_in[0];
  const int*   edge_vec     = (const int*)d_in[1];
  const float* n2e          = (const float*)d_in[2];
  const float* e2n          = (const float*)d_in[3];
  const float* Wtensor      = (const float*)d_in[4];
  const float* Wz           = (const float*)d_in[5];
  const float* Wr           = (const float*)d_in[6];
  const float* Wt           = (const float*)d_in[7];
  const float* Wf           = (const float*)d_in[8];
  const float* bf           = (const float*)d_in[9];
  float* out = (float*)d_out;

  char* p = (char*)d_ws;
  int* src   = (int*)p; p += Bb*Ee*4;
  int* tgt   = (int*)p; p += Bb*Ee*4;
  int* order = (int*)p; p += Bb*Ee*4;
  int* offs  = (int*)p; p += 4096;
  float* WT  = (float*)p; p += (size_t)Tt*Hh*Hh*4;
  float* Ff  = (float*)p; p += (size_t)384*Hh*4;
  float* bwp = (float*)p; p += (size_t)Bb*Nn*Hh*4;
  float* fwp = (float*)p; p += (size_t)Bb*Nn*Hh*4;
  float* h1  = (float*)p; p += (size_t)Bb*Nn*Hh*4;

  k_extract<<<1024, 256, 0, stream>>>((const float4*)n2e, (const float4*)e2n, src, tgt);
  k_transW<<<(Tt*Hh*Hh + 255)/256, 256, 0, stream>>>(Wtensor, WT);
  k_prep<<<(384*Hh + 255)/256, 256, 0, stream>>>(Wf, Ff);
  k_sort<<<Bb, 256, 0, stream>>>(edge_vec, order, offs);
  hipMemsetAsync(bwp, 0, (size_t)2*Bb*Nn*Hh*4, stream);   // bw+fw zero (once; hops re-zero in epilogue)

  const float* hin = node_feature;
  float* houts[3] = { out, h1, out };
  for (int hop = 0; hop < 3; ++hop){
    k_edge_mp<<<dim3(Bb*Tt*2, 4), 256, 0, stream>>>(hin, WT, order, offs, src, tgt, bwp, fwp);
    k_fuse_gru<<<(Bb*Nn)/16, 512, 0, stream>>>(hin, fwp, bwp, Ff, bf, Wz, Wr, Wt, houts[hop], fwp, bwp);
    hin = houts[hop];
  }
}